// Round 2
// baseline (170.595 us; speedup 1.0000x reference)
//
#include <hip/hip_runtime.h>
#include <math.h>

#define Bc 4
#define Vc 4
#define Hc 256
#define Wc 384
#define HWc (Hc*Wc)               // 98304
#define TOTc (Bc*Vc*HWc)          // 1572864
#define SCALE_MIN_c 1e-05f
#define SCALE_MAX_c 30.0f
#define EPS_c 1e-08f

// Output section offsets (in floats)
#define MEANS_OFF  ((size_t)0)
#define SCALES_OFF ((size_t)TOTc*3)
#define ROT_OFF    ((size_t)TOTc*6)
#define HARM_OFF   ((size_t)TOTc*10)
#define OPAC_OFF   ((size_t)TOTc*13)

__global__ __launch_bounds__(256) void ga_kernel(
    const float* __restrict__ ext,    // (B,V,4,4)
    const float* __restrict__ intr,   // (B,V,3,3)
    const float* __restrict__ depths, // (B,V,H,W)
    const float* __restrict__ opac,   // (B,V,H,W)
    const float* __restrict__ raw,    // (B,V,H,W,12)
    float* __restrict__ out)
{
    __shared__ float sR[9];   // Rc2w row-major
    __shared__ float sO[3];   // camera origin (world)
    __shared__ float sK[9];   // Kinv of normalized intrinsics
    __shared__ float sQ[4];   // c2w quaternion wxyz
    __shared__ float sMult;   // scale multiplier
    // Output staging: [0,768) means, [768,1536) scales, [1536,2304) harmonics
    __shared__ float sOut[2304];

    const int tid = threadIdx.x;
    const int g   = blockIdx.x * 256 + tid;

    // Issue per-pixel loads EARLY (before the constants barrier) for latency hiding.
    const float4* rp = reinterpret_cast<const float4*>(raw + (size_t)g * 12);
    const float4 r0 = rp[0];   // raw[0..3]
    const float4 r1 = rp[1];   // raw[4..7]
    const float4 r2 = rp[2];   // raw[8..11]
    const float dep = depths[g];
    const float op  = opac[g];

    if (tid == 0) {
        const int view = blockIdx.x / (HWc / 256);   // 0..15, uniform per block
        const float* E = ext + view * 16;
        // Rc2w = Rw2c^T ; Rw2c rows are E[0..2], E[4..6], E[8..10]
        float R[9];
        #pragma unroll
        for (int i = 0; i < 3; i++)
            #pragma unroll
            for (int j = 0; j < 3; j++)
                R[i*3+j] = E[j*4+i];
        const float t0 = E[3], t1 = E[7], t2 = E[11];
        sO[0] = -(R[0]*t0 + R[1]*t1 + R[2]*t2);
        sO[1] = -(R[3]*t0 + R[4]*t1 + R[5]*t2);
        sO[2] = -(R[6]*t0 + R[7]*t1 + R[8]*t2);
        #pragma unroll
        for (int k = 0; k < 9; k++) sR[k] = R[k];

        // normalized intrinsics: row0 /= W, row1 /= H
        const float* I = intr + view * 9;
        const float a00 = I[0]*(1.0f/Wc), a01 = I[1]*(1.0f/Wc), a02 = I[2]*(1.0f/Wc);
        const float a10 = I[3]*(1.0f/Hc), a11 = I[4]*(1.0f/Hc), a12 = I[5]*(1.0f/Hc);
        const float a20 = I[6],           a21 = I[7],           a22 = I[8];
        const float det = a00*(a11*a22 - a12*a21)
                        - a01*(a10*a22 - a12*a20)
                        + a02*(a10*a21 - a11*a20);
        const float id = 1.0f / det;
        sK[0] = (a11*a22 - a12*a21)*id;
        sK[1] = (a02*a21 - a01*a22)*id;
        sK[2] = (a01*a12 - a02*a11)*id;
        sK[3] = (a12*a20 - a10*a22)*id;
        sK[4] = (a00*a22 - a02*a20)*id;
        sK[5] = (a02*a10 - a00*a12)*id;
        sK[6] = (a10*a21 - a11*a20)*id;
        sK[7] = (a01*a20 - a00*a21)*id;
        sK[8] = (a00*a11 - a01*a10)*id;

        // mult = 0.1 * sum(inv(k2) @ pixel_size)
        const float det2 = a00*a11 - a01*a10;
        const float psx = 1.0f/Wc, psy = 1.0f/Hc;
        sMult = 0.1f * ((a11*psx - a01*psy) + (-a10*psx + a00*psy)) / det2;

        // c2w quaternion from Rc2w (matches _mat_to_quat_wxyz)
        const float m00 = R[0], m01 = R[1], m02 = R[2];
        const float m10 = R[3], m11 = R[4], m12 = R[5];
        const float m20 = R[6], m21 = R[7], m22 = R[8];
        float qa[4];
        qa[0] = sqrtf(fmaxf(0.0f, 1.0f + m00 + m11 + m22));
        qa[1] = sqrtf(fmaxf(0.0f, 1.0f + m00 - m11 - m22));
        qa[2] = sqrtf(fmaxf(0.0f, 1.0f - m00 + m11 - m22));
        qa[3] = sqrtf(fmaxf(0.0f, 1.0f - m00 - m11 + m22));
        float cand[4][4] = {
            { qa[0]*qa[0], m21 - m12,   m02 - m20,   m10 - m01 },
            { m21 - m12,   qa[1]*qa[1], m10 + m01,   m02 + m20 },
            { m02 - m20,   m10 + m01,   qa[2]*qa[2], m12 + m21 },
            { m10 - m01,   m20 + m02,   m21 + m12,   qa[3]*qa[3] } };
        int idx = 0;
        if (qa[1] > qa[idx]) idx = 1;
        if (qa[2] > qa[idx]) idx = 2;
        if (qa[3] > qa[idx]) idx = 3;
        const float dd = 1.0f / (2.0f * fmaxf(qa[idx], 0.1f));
        float q0 = cand[idx][0]*dd, q1 = cand[idx][1]*dd,
              q2 = cand[idx][2]*dd, q3 = cand[idx][3]*dd;
        const float qn = 1.0f / sqrtf(q0*q0 + q1*q1 + q2*q2 + q3*q3);
        sQ[0] = q0*qn; sQ[1] = q1*qn; sQ[2] = q2*qn; sQ[3] = q3*qn;
    }
    __syncthreads();

    // ---- per-pixel work ----
    const int pix = g % HWc;
    const int h = pix / Wc;
    const int w = pix % Wc;

    const float x = (w + 0.5f) * (1.0f/Wc) + r0.x * (1.0f/Wc);
    const float y = (h + 0.5f) * (1.0f/Hc) + r0.y * (1.0f/Hc);

    // d_cam = normalize(Kinv @ (x,y,1))
    float dc0 = sK[0]*x + sK[1]*y + sK[2];
    float dc1 = sK[3]*x + sK[4]*y + sK[5];
    float dc2 = sK[6]*x + sK[7]*y + sK[8];
    const float inl = rsqrtf(dc0*dc0 + dc1*dc1 + dc2*dc2);
    dc0 *= inl; dc1 *= inl; dc2 *= inl;

    // d_world = Rc2w @ d_cam
    const float dw0 = sR[0]*dc0 + sR[1]*dc1 + sR[2]*dc2;
    const float dw1 = sR[3]*dc0 + sR[4]*dc1 + sR[5]*dc2;
    const float dw2 = sR[6]*dc0 + sR[7]*dc1 + sR[8]*dc2;

    // means -> LDS staging (stride-3 dwords: 2-way bank alias, free)
    sOut[tid*3 + 0] = sO[0] + dw0 * dep;
    sOut[tid*3 + 1] = sO[1] + dw1 * dep;
    sOut[tid*3 + 2] = sO[2] + dw2 * dep;

    // scales: (SCALE_MIN + range*sigmoid(raw[2:5])) * depth * mult -> LDS
    const float sm = dep * sMult;
    sOut[768 + tid*3 + 0] = (SCALE_MIN_c + (SCALE_MAX_c - SCALE_MIN_c) / (1.0f + __expf(-r0.z))) * sm;
    sOut[768 + tid*3 + 1] = (SCALE_MIN_c + (SCALE_MAX_c - SCALE_MIN_c) / (1.0f + __expf(-r0.w))) * sm;
    sOut[768 + tid*3 + 2] = (SCALE_MIN_c + (SCALE_MAX_c - SCALE_MIN_c) / (1.0f + __expf(-r1.x))) * sm;

    // rotations: normalize raw[5:9] (xyzw) -> wxyz, then c2w_q * cam_q (direct f4 store)
    const float rx = r1.y, ry = r1.z, rz = r1.w, rw = r2.x;
    const float rn = 1.0f / (sqrtf(rx*rx + ry*ry + rz*rz + rw*rw) + EPS_c);
    const float bw = rw*rn, bx = rx*rn, by = ry*rn, bz = rz*rn;
    const float aw = sQ[0], ax = sQ[1], ay = sQ[2], az = sQ[3];
    float4 wq;
    wq.x = aw*bw - ax*bx - ay*by - az*bz;
    wq.y = aw*bx + ax*bw + ay*bz - az*by;
    wq.z = aw*by - ax*bz + ay*bw + az*bx;
    wq.w = aw*bz + ax*by - ay*bx + az*bw;
    reinterpret_cast<float4*>(out + ROT_OFF)[g] = wq;

    // harmonics -> LDS
    sOut[1536 + tid*3 + 0] = r2.y;
    sOut[1536 + tid*3 + 1] = r2.z;
    sOut[1536 + tid*3 + 2] = r2.w;

    // opacity passthrough (coalesced dword)
    out[OPAC_OFF + g] = op;

    __syncthreads();

    // ---- coalesced float4 write-out of the three staged sections ----
    // 576 float4 total: [0,192) means, [192,384) scales, [384,576) harmonics
    const float4* sv = reinterpret_cast<const float4*>(sOut);
    #pragma unroll
    for (int i = tid; i < 576; i += 256) {
        const int sec = i / 192;        // 0,1,2  (wave-uniform within an iteration mostly)
        const int j   = i - sec * 192;
        const size_t base = (sec == 0 ? MEANS_OFF : (sec == 1 ? SCALES_OFF : HARM_OFF))
                          + (size_t)blockIdx.x * 768;
        reinterpret_cast<float4*>(out + base)[j] = sv[i];
    }
}

extern "C" void kernel_launch(void* const* d_in, const int* in_sizes, int n_in,
                              void* d_out, int out_size, void* d_ws, size_t ws_size,
                              hipStream_t stream) {
    const float* ext    = (const float*)d_in[0];
    const float* intr   = (const float*)d_in[1];
    const float* depths = (const float*)d_in[2];
    const float* opac   = (const float*)d_in[3];
    const float* raw    = (const float*)d_in[4];
    float* out = (float*)d_out;

    ga_kernel<<<TOTc / 256, 256, 0, stream>>>(ext, intr, depths, opac, raw, out);
}

// Round 3
// 170.248 us; speedup vs baseline: 1.0020x; 1.0020x over previous
//
#include <hip/hip_runtime.h>
#include <math.h>

#define Bc 4
#define Vc 4
#define Hc 256
#define Wc 384
#define HWc (Hc*Wc)               // 98304
#define TOTc (Bc*Vc*HWc)          // 1572864
#define SCALE_MIN_c 1e-05f
#define SCALE_MAX_c 30.0f
#define EPS_c 1e-08f

// Output section offsets (in floats)
#define MEANS_OFF  ((size_t)0)
#define SCALES_OFF ((size_t)TOTc*3)
#define ROT_OFF    ((size_t)TOTc*6)
#define HARM_OFF   ((size_t)TOTc*10)
#define OPAC_OFF   ((size_t)TOTc*13)

__device__ __forceinline__ void async_copy16(const float4* g, float4* l) {
    __builtin_amdgcn_global_load_lds(
        (const __attribute__((address_space(1))) void*)g,
        (__attribute__((address_space(3))) void*)l,
        16, 0, 0);
}

__global__ __launch_bounds__(256) void ga_kernel(
    const float* __restrict__ ext,    // (B,V,4,4)
    const float* __restrict__ intr,   // (B,V,3,3)
    const float* __restrict__ depths, // (B,V,H,W)
    const float* __restrict__ opac,   // (B,V,H,W)
    const float* __restrict__ raw,    // (B,V,H,W,12)
    float* __restrict__ out)
{
    __shared__ float4 sRaw[768];      // 12 KB: block's raw gaussians, flat coalesced order
    __shared__ float sR[9];           // Rc2w row-major
    __shared__ float sO[3];           // camera origin (world)
    __shared__ float sK[9];           // Kinv of normalized intrinsics
    __shared__ float sQ[4];           // c2w quaternion wxyz
    __shared__ float sMult;           // scale multiplier
    // Output staging: [0,768) means, [768,1536) scales, [1536,2304) harmonics
    __shared__ float sOut[2304];

    const int tid = threadIdx.x;
    const int g   = blockIdx.x * 256 + tid;

    // ---- coalesced async staging of raw gaussians: 3 x 256 float4 per block ----
    // Each wave DMAs 64 contiguous float4 (1 KB) per call; LDS dest = uniform base + lane*16.
    {
        const float4* gbase = reinterpret_cast<const float4*>(raw) + (size_t)blockIdx.x * 768;
        const int waveBase = tid & 192;       // wave-uniform
        async_copy16(gbase +   0 + tid, &sRaw[  0 + waveBase]);
        async_copy16(gbase + 256 + tid, &sRaw[256 + waveBase]);
        async_copy16(gbase + 512 + tid, &sRaw[512 + waveBase]);
    }

    // coalesced scalar loads (issued early, consumed after barrier)
    const float dep = depths[g];
    const float op  = opac[g];

    if (tid == 0) {
        const int view = blockIdx.x / (HWc / 256);   // 0..15, uniform per block
        const float* E = ext + view * 16;
        // Rc2w = Rw2c^T ; Rw2c rows are E[0..2], E[4..6], E[8..10]
        float R[9];
        #pragma unroll
        for (int i = 0; i < 3; i++)
            #pragma unroll
            for (int j = 0; j < 3; j++)
                R[i*3+j] = E[j*4+i];
        const float t0 = E[3], t1 = E[7], t2 = E[11];
        sO[0] = -(R[0]*t0 + R[1]*t1 + R[2]*t2);
        sO[1] = -(R[3]*t0 + R[4]*t1 + R[5]*t2);
        sO[2] = -(R[6]*t0 + R[7]*t1 + R[8]*t2);
        #pragma unroll
        for (int k = 0; k < 9; k++) sR[k] = R[k];

        // normalized intrinsics: row0 /= W, row1 /= H
        const float* I = intr + view * 9;
        const float a00 = I[0]*(1.0f/Wc), a01 = I[1]*(1.0f/Wc), a02 = I[2]*(1.0f/Wc);
        const float a10 = I[3]*(1.0f/Hc), a11 = I[4]*(1.0f/Hc), a12 = I[5]*(1.0f/Hc);
        const float a20 = I[6],           a21 = I[7],           a22 = I[8];
        const float det = a00*(a11*a22 - a12*a21)
                        - a01*(a10*a22 - a12*a20)
                        + a02*(a10*a21 - a11*a20);
        const float id = 1.0f / det;
        sK[0] = (a11*a22 - a12*a21)*id;
        sK[1] = (a02*a21 - a01*a22)*id;
        sK[2] = (a01*a12 - a02*a11)*id;
        sK[3] = (a12*a20 - a10*a22)*id;
        sK[4] = (a00*a22 - a02*a20)*id;
        sK[5] = (a02*a10 - a00*a12)*id;
        sK[6] = (a10*a21 - a11*a20)*id;
        sK[7] = (a01*a20 - a00*a21)*id;
        sK[8] = (a00*a11 - a01*a10)*id;

        // mult = 0.1 * sum(inv(k2) @ pixel_size)
        const float det2 = a00*a11 - a01*a10;
        const float psx = 1.0f/Wc, psy = 1.0f/Hc;
        sMult = 0.1f * ((a11*psx - a01*psy) + (-a10*psx + a00*psy)) / det2;

        // c2w quaternion from Rc2w (matches _mat_to_quat_wxyz)
        const float m00 = R[0], m01 = R[1], m02 = R[2];
        const float m10 = R[3], m11 = R[4], m12 = R[5];
        const float m20 = R[6], m21 = R[7], m22 = R[8];
        float qa[4];
        qa[0] = sqrtf(fmaxf(0.0f, 1.0f + m00 + m11 + m22));
        qa[1] = sqrtf(fmaxf(0.0f, 1.0f + m00 - m11 - m22));
        qa[2] = sqrtf(fmaxf(0.0f, 1.0f - m00 + m11 - m22));
        qa[3] = sqrtf(fmaxf(0.0f, 1.0f - m00 - m11 + m22));
        float cand[4][4] = {
            { qa[0]*qa[0], m21 - m12,   m02 - m20,   m10 - m01 },
            { m21 - m12,   qa[1]*qa[1], m10 + m01,   m02 + m20 },
            { m02 - m20,   m10 + m01,   qa[2]*qa[2], m12 + m21 },
            { m10 - m01,   m20 + m02,   m21 + m12,   qa[3]*qa[3] } };
        int idx = 0;
        if (qa[1] > qa[idx]) idx = 1;
        if (qa[2] > qa[idx]) idx = 2;
        if (qa[3] > qa[idx]) idx = 3;
        const float dd = 1.0f / (2.0f * fmaxf(qa[idx], 0.1f));
        float q0 = cand[idx][0]*dd, q1 = cand[idx][1]*dd,
              q2 = cand[idx][2]*dd, q3 = cand[idx][3]*dd;
        const float qn = 1.0f / sqrtf(q0*q0 + q1*q1 + q2*q2 + q3*q3);
        sQ[0] = q0*qn; sQ[1] = q1*qn; sQ[2] = q2*qn; sQ[3] = q3*qn;
    }
    __syncthreads();   // drains global_load_lds (vmcnt) + publishes constants

    // ---- gather this pixel's 12 floats from LDS (3x ds_read_b128, 48 B stride) ----
    const float4 r0 = sRaw[tid*3 + 0];   // raw[0..3]
    const float4 r1 = sRaw[tid*3 + 1];   // raw[4..7]
    const float4 r2 = sRaw[tid*3 + 2];   // raw[8..11]

    // ---- per-pixel work ----
    const int pix = g % HWc;
    const int h = pix / Wc;
    const int w = pix % Wc;

    const float x = (w + 0.5f) * (1.0f/Wc) + r0.x * (1.0f/Wc);
    const float y = (h + 0.5f) * (1.0f/Hc) + r0.y * (1.0f/Hc);

    // d_cam = normalize(Kinv @ (x,y,1))
    float dc0 = sK[0]*x + sK[1]*y + sK[2];
    float dc1 = sK[3]*x + sK[4]*y + sK[5];
    float dc2 = sK[6]*x + sK[7]*y + sK[8];
    const float inl = rsqrtf(dc0*dc0 + dc1*dc1 + dc2*dc2);
    dc0 *= inl; dc1 *= inl; dc2 *= inl;

    // d_world = Rc2w @ d_cam
    const float dw0 = sR[0]*dc0 + sR[1]*dc1 + sR[2]*dc2;
    const float dw1 = sR[3]*dc0 + sR[4]*dc1 + sR[5]*dc2;
    const float dw2 = sR[6]*dc0 + sR[7]*dc1 + sR[8]*dc2;

    // means -> LDS staging (stride-3 dwords: 2-way bank alias, free)
    sOut[tid*3 + 0] = sO[0] + dw0 * dep;
    sOut[tid*3 + 1] = sO[1] + dw1 * dep;
    sOut[tid*3 + 2] = sO[2] + dw2 * dep;

    // scales: (SCALE_MIN + range*sigmoid(raw[2:5])) * depth * mult -> LDS
    const float sm = dep * sMult;
    sOut[768 + tid*3 + 0] = (SCALE_MIN_c + (SCALE_MAX_c - SCALE_MIN_c) / (1.0f + __expf(-r0.z))) * sm;
    sOut[768 + tid*3 + 1] = (SCALE_MIN_c + (SCALE_MAX_c - SCALE_MIN_c) / (1.0f + __expf(-r0.w))) * sm;
    sOut[768 + tid*3 + 2] = (SCALE_MIN_c + (SCALE_MAX_c - SCALE_MIN_c) / (1.0f + __expf(-r1.x))) * sm;

    // rotations: normalize raw[5:9] (xyzw) -> wxyz, then c2w_q * cam_q (direct f4 store)
    const float rx = r1.y, ry = r1.z, rz = r1.w, rw = r2.x;
    const float rn = 1.0f / (sqrtf(rx*rx + ry*ry + rz*rz + rw*rw) + EPS_c);
    const float bw = rw*rn, bx = rx*rn, by = ry*rn, bz = rz*rn;
    const float aw = sQ[0], ax = sQ[1], ay = sQ[2], az = sQ[3];
    float4 wq;
    wq.x = aw*bw - ax*bx - ay*by - az*bz;
    wq.y = aw*bx + ax*bw + ay*bz - az*by;
    wq.z = aw*by - ax*bz + ay*bw + az*bx;
    wq.w = aw*bz + ax*by - ay*bx + az*bw;
    reinterpret_cast<float4*>(out + ROT_OFF)[g] = wq;

    // harmonics -> LDS
    sOut[1536 + tid*3 + 0] = r2.y;
    sOut[1536 + tid*3 + 1] = r2.z;
    sOut[1536 + tid*3 + 2] = r2.w;

    // opacity passthrough (coalesced dword)
    out[OPAC_OFF + g] = op;

    __syncthreads();

    // ---- coalesced float4 write-out of the three staged sections ----
    // 576 float4 total: [0,192) means, [192,384) scales, [384,576) harmonics
    const float4* sv = reinterpret_cast<const float4*>(sOut);
    #pragma unroll
    for (int i = tid; i < 576; i += 256) {
        const int sec = i / 192;
        const int j   = i - sec * 192;
        const size_t base = (sec == 0 ? MEANS_OFF : (sec == 1 ? SCALES_OFF : HARM_OFF))
                          + (size_t)blockIdx.x * 768;
        reinterpret_cast<float4*>(out + base)[j] = sv[i];
    }
}

extern "C" void kernel_launch(void* const* d_in, const int* in_sizes, int n_in,
                              void* d_out, int out_size, void* d_ws, size_t ws_size,
                              hipStream_t stream) {
    const float* ext    = (const float*)d_in[0];
    const float* intr   = (const float*)d_in[1];
    const float* depths = (const float*)d_in[2];
    const float* opac   = (const float*)d_in[3];
    const float* raw    = (const float*)d_in[4];
    float* out = (float*)d_out;

    ga_kernel<<<TOTc / 256, 256, 0, stream>>>(ext, intr, depths, opac, raw, out);
}